// Round 7
// baseline (971.672 us; speedup 1.0000x reference)
//
#include <hip/hip_runtime.h>
#include <math.h>

// DenseCaps dynamic routing, MI355X. B=32, I=4096, O=32, 4x4 poses, 3 iters.
// R6 post-mortem: f16 votes were NEUTRAL -> passes (~25us) are NOT issue-bound
// (floor ~6us); bottleneck is in the shared structure. This round: kill the
// 3 reduce kernels + 16.8MB partial round-trips. Passes atomicAdd s-partials
// into 4 chunk-keyed replicas (64KB each); each next pass recomputes v
// locally from prior replicas (64KB read/block, ~100 FLOP/thread). 5
// dispatches total: memset(3MB) + 3 passes + final squash. fp32 vote path
// (R5-proven); softmax without max-shift, DPP+swizzle 32-lane sum.

#define NB 32
#define NI 4096
#define NO 32
#define I_TILE 16
#define NCHUNK (NI / I_TILE)        // 256
#define B_TILE 8
#define NBG (NB / B_TILE)           // 4
#define KREP 4
#define WSTR_I 578                  // LDS words per i-slab: 32*18 + 2
#define WSTR_O 18                   // padded words per o-row
#define SOFF (NB * NO * 16)         // 16384 floats per replica slab
#define EPSF 1e-12f

__device__ __forceinline__ float4 row_mm(const float4 p, const float4 w0,
                                         const float4 w1, const float4 w2,
                                         const float4 w3) {
    float4 r;
    r.x = fmaf(p.x, w0.x, fmaf(p.y, w1.x, fmaf(p.z, w2.x, p.w * w3.x)));
    r.y = fmaf(p.x, w0.y, fmaf(p.y, w1.y, fmaf(p.z, w2.y, p.w * w3.y)));
    r.z = fmaf(p.x, w0.z, fmaf(p.y, w1.z, fmaf(p.z, w2.z, p.w * w3.z)));
    r.w = fmaf(p.x, w0.w, fmaf(p.y, w1.w, fmaf(p.z, w2.w, p.w * w3.w)));
    return r;
}

__device__ __forceinline__ float dot4(const float4 a, const float4 b) {
    return fmaf(a.x, b.x, fmaf(a.y, b.y, fmaf(a.z, b.z, a.w * b.w)));
}

__device__ __forceinline__ void fma4(float4& s, const float c, const float4 t) {
    s.x = fmaf(c, t.x, s.x);
    s.y = fmaf(c, t.y, s.y);
    s.z = fmaf(c, t.z, s.z);
    s.w = fmaf(c, t.w, s.w);
}

__device__ __forceinline__ void add4(float4& s, const float4 t) {
    s.x += t.x; s.y += t.y; s.z += t.z; s.w += t.w;
}

// x + dpp_perm(x); ctrl: 0xB1=quad_perm xor1, 0x4E=quad_perm xor2,
// 0x141=row_half_mirror (xor7), 0x140=row_mirror (xor15).
template <int CTRL>
__device__ __forceinline__ float dpp_add(float x) {
    int xi = __builtin_bit_cast(int, x);
    int yi = __builtin_amdgcn_update_dpp(0, xi, CTRL, 0xf, 0xf, false);
    return x + __builtin_bit_cast(float, yi);
}

// sum over each 32-lane half (the o-group)
__device__ __forceinline__ float sum32(float x) {
    x = dpp_add<0xB1>(x);    // xor1
    x = dpp_add<0x4E>(x);    // xor2
    x = dpp_add<0x141>(x);   // xor7 -> with above spans xor4
    x = dpp_add<0x140>(x);   // xor15 -> spans xor8 (row of 16 done)
    int t = __builtin_amdgcn_ds_swizzle(__builtin_bit_cast(int, x), 0x401F);
    return x + __builtin_bit_cast(float, t);   // xor16 within 32-lane group
}

// ---------------- pass kernel (atomic replicas, local v recompute) --------
__global__ __launch_bounds__(256, 4) void caps_pass_at(
    const float* __restrict__ poses, const float* __restrict__ w,
    float* __restrict__ rep, const int pass)
{
    __shared__ float wsm[I_TILE * WSTR_I];   // 36992 B
    const int tid    = threadIdx.x;
    const int chunk  = blockIdx.x;
    const int bgroup = blockIdx.y;
    const int ibase  = chunk * I_TILE;

    // stage w tile, fully coalesced (each wave reads one o's contiguous 1KB)
    #pragma unroll
    for (int r = 0; r < 8; ++r) {
        const int idx = r * 256 + tid;
        const int o_l = idx >> 6;
        const int rem = idx & 63;
        const int i_l = rem >> 2;
        const int k4  = rem & 3;
        const float4 val = *(const float4*)(
            w + (((size_t)o_l * NI + ibase + i_l) << 4) + (k4 << 2));
        float* dst = &wsm[i_l * WSTR_I + o_l * WSTR_O + (k4 << 2)];
        ((float2*)dst)[0] = make_float2(val.x, val.y);
        ((float2*)dst)[1] = make_float2(val.z, val.w);
    }

    const int o    = tid & 31;
    const int bsub = tid >> 5;
    const int b    = bgroup * B_TILE + bsub;
    const int bo   = b * NO + o;

    // Recompute v_sum = sum_{t<pass} squash(s_t) from prior-pass replicas.
    float4 vv0 = {0,0,0,0}, vv1 = {0,0,0,0}, vv2 = {0,0,0,0}, vv3 = {0,0,0,0};
    for (int t = 0; t < pass; ++t) {
        float4 a0 = {0,0,0,0}, a1 = {0,0,0,0}, a2 = {0,0,0,0}, a3 = {0,0,0,0};
        #pragma unroll
        for (int r = 0; r < KREP; ++r) {
            const float4* q = (const float4*)(
                rep + (size_t)(t * KREP + r) * SOFF + (bo << 4));
            add4(a0, q[0]); add4(a1, q[1]); add4(a2, q[2]); add4(a3, q[3]);
        }
        const float n2 = dot4(a0,a0) + dot4(a1,a1) + dot4(a2,a2) + dot4(a3,a3);
        const float n  = sqrtf(n2 + EPSF);
        const float sc = (n2 / (1.0f + n2)) / n;
        fma4(vv0, sc, a0); fma4(vv1, sc, a1);
        fma4(vv2, sc, a2); fma4(vv3, sc, a3);
    }

    const float*  wrow  = &wsm[o * WSTR_O];
    const float4* pbase = (const float4*)(poses + (((size_t)b * NI + ibase) << 4));

    __syncthreads();

    float4 s0 = {0,0,0,0}, s1 = {0,0,0,0}, s2 = {0,0,0,0}, s3 = {0,0,0,0};

    #pragma unroll 2
    for (int i = 0; i < I_TILE; ++i) {
        const float2* wr = (const float2*)(wrow + i * WSTR_I);
        const float2 a0 = wr[0], a1 = wr[1], a2 = wr[2], a3 = wr[3];
        const float2 a4 = wr[4], a5 = wr[5], a6 = wr[6], a7 = wr[7];
        const float4 w0 = make_float4(a0.x, a0.y, a1.x, a1.y);
        const float4 w1 = make_float4(a2.x, a2.y, a3.x, a3.y);
        const float4 w2 = make_float4(a4.x, a4.y, a5.x, a5.y);
        const float4 w3 = make_float4(a6.x, a6.y, a7.x, a7.y);
        const float4 p0 = pbase[(i << 2) + 0];
        const float4 p1 = pbase[(i << 2) + 1];
        const float4 p2 = pbase[(i << 2) + 2];
        const float4 p3 = pbase[(i << 2) + 3];

        const float4 t0 = row_mm(p0, w0, w1, w2, w3);
        const float4 t1 = row_mm(p1, w0, w1, w2, w3);
        const float4 t2 = row_mm(p2, w0, w1, w2, w3);
        const float4 t3 = row_mm(p3, w0, w1, w2, w3);

        float cc;
        if (pass == 0) {
            cc = 1.0f / 32.0f;
        } else {
            // softmax over o without max-shift: |d| bounded (~<4), exp safe.
            const float d = dot4(t0,vv0) + dot4(t1,vv1)
                          + dot4(t2,vv2) + dot4(t3,vv3);
            const float e  = __expf(d);
            const float es = sum32(e);
            cc = __fdividef(e, es);
        }
        fma4(s0, cc, t0); fma4(s1, cc, t1);
        fma4(s2, cc, t2); fma4(s3, cc, t3);
    }

    // atomic accumulate into chunk-keyed replica (64-way/address worst case)
    float* sb = rep + (size_t)(pass * KREP + (chunk & (KREP - 1))) * SOFF
              + (bo << 4);
    atomicAdd(sb +  0, s0.x); atomicAdd(sb +  1, s0.y);
    atomicAdd(sb +  2, s0.z); atomicAdd(sb +  3, s0.w);
    atomicAdd(sb +  4, s1.x); atomicAdd(sb +  5, s1.y);
    atomicAdd(sb +  6, s1.z); atomicAdd(sb +  7, s1.w);
    atomicAdd(sb +  8, s2.x); atomicAdd(sb +  9, s2.y);
    atomicAdd(sb + 10, s2.z); atomicAdd(sb + 11, s2.w);
    atomicAdd(sb + 12, s3.x); atomicAdd(sb + 13, s3.y);
    atomicAdd(sb + 14, s3.z); atomicAdd(sb + 15, s3.w);
}

// ---------------- final squash ----------------
__global__ __launch_bounds__(256) void caps_final(
    const float* __restrict__ rep, float* __restrict__ out)
{
    const int bo = blockIdx.x * 256 + threadIdx.x;
    if (bo >= NB * NO) return;
    float4 a0 = {0,0,0,0}, a1 = {0,0,0,0}, a2 = {0,0,0,0}, a3 = {0,0,0,0};
    #pragma unroll
    for (int r = 0; r < KREP; ++r) {
        const float4* q = (const float4*)(
            rep + (size_t)(2 * KREP + r) * SOFF + (bo << 4));
        add4(a0, q[0]); add4(a1, q[1]); add4(a2, q[2]); add4(a3, q[3]);
    }
    const float n2 = dot4(a0,a0) + dot4(a1,a1) + dot4(a2,a2) + dot4(a3,a3);
    const float n  = sqrtf(n2 + EPSF);
    const float sc = (n2 / (1.0f + n2)) / n;
    float4* op = (float4*)(out + (bo << 4));
    op[0] = make_float4(sc*a0.x, sc*a0.y, sc*a0.z, sc*a0.w);
    op[1] = make_float4(sc*a1.x, sc*a1.y, sc*a1.z, sc*a1.w);
    op[2] = make_float4(sc*a2.x, sc*a2.y, sc*a2.z, sc*a2.w);
    op[3] = make_float4(sc*a3.x, sc*a3.y, sc*a3.z, sc*a3.w);
    out[NB * NO * 16 + bo] = sqrtf(n2 * sc * sc + EPSF);
}

// ---------------- fallback: proven v1-style kernels (tiny ws) -------------
#define FB_CHUNKS 32
#define FB_IPB (NI / FB_CHUNKS)

__global__ __launch_bounds__(256) void caps_pass_fb(
    const float* __restrict__ poses, const float* __restrict__ w,
    const float* __restrict__ v_buf, float* __restrict__ s_buf, const int mode)
{
    const int tid   = threadIdx.x;
    const int b     = blockIdx.y;
    const int chunk = blockIdx.x;
    const int o     = tid & 31;
    const int g     = tid >> 5;

    float4 v0 = {0,0,0,0}, v1 = {0,0,0,0}, v2 = {0,0,0,0}, v3 = {0,0,0,0};
    if (mode != 0) {
        const float4* vp = (const float4*)(v_buf + (((b * NO) + o) << 4));
        v0 = vp[0]; v1 = vp[1]; v2 = vp[2]; v3 = vp[3];
    }
    float4 s0 = {0,0,0,0}, s1 = {0,0,0,0}, s2 = {0,0,0,0}, s3 = {0,0,0,0};
    const int ibase = chunk * FB_IPB + g;
    #pragma unroll 4
    for (int it = 0; it < FB_IPB / 8; ++it) {
        const int i = ibase + (it << 3);
        const float4* ppf = (const float4*)(poses + ((((size_t)b * NI) + i) << 4));
        const float4 p0 = ppf[0], p1 = ppf[1], p2 = ppf[2], p3 = ppf[3];
        const float4* wpf = (const float4*)(w + ((((size_t)o * NI) + i) << 4));
        const float4 w0 = wpf[0], w1 = wpf[1], w2 = wpf[2], w3 = wpf[3];
        const float4 t0 = row_mm(p0, w0, w1, w2, w3);
        const float4 t1 = row_mm(p1, w0, w1, w2, w3);
        const float4 t2 = row_mm(p2, w0, w1, w2, w3);
        const float4 t3 = row_mm(p3, w0, w1, w2, w3);
        float cc;
        if (mode == 0) {
            cc = 1.0f / 32.0f;
        } else {
            float d = dot4(t0,v0) + dot4(t1,v1) + dot4(t2,v2) + dot4(t3,v3);
            const float e  = __expf(d);
            const float es = sum32(e);
            cc = __fdividef(e, es);
        }
        fma4(s0, cc, t0); fma4(s1, cc, t1);
        fma4(s2, cc, t2); fma4(s3, cc, t3);
    }
    __shared__ float red[8][32][16];
    float4* rp = (float4*)&red[g][o][0];
    rp[0] = s0; rp[1] = s1; rp[2] = s2; rp[3] = s3;
    __syncthreads();
    for (int idx = tid; idx < NO * 16; idx += 256) {
        const int oo = idx >> 4;
        const int k  = idx & 15;
        float acc = red[0][oo][k];
        #pragma unroll
        for (int gg = 1; gg < 8; ++gg) acc += red[gg][oo][k];
        atomicAdd(&s_buf[(((b * NO) + oo) << 4) + k], acc);
    }
}

__global__ __launch_bounds__(256) void caps_squash_fb(
    float* __restrict__ s_buf, float* __restrict__ v_buf,
    float* __restrict__ out, const int mode)
{
    const int idx = blockIdx.x * 256 + threadIdx.x;
    if (idx >= NB * NO) return;
    float4* sp = (float4*)(s_buf + (idx << 4));
    const float4 s0 = sp[0], s1 = sp[1], s2 = sp[2], s3 = sp[3];
    const float n2 = dot4(s0,s0) + dot4(s1,s1) + dot4(s2,s2) + dot4(s3,s3);
    const float n  = sqrtf(n2 + EPSF);
    const float sc = (n2 / (1.0f + n2)) / n;
    if (mode == 2) {
        float4* op = (float4*)(out + (idx << 4));
        op[0] = make_float4(sc*s0.x, sc*s0.y, sc*s0.z, sc*s0.w);
        op[1] = make_float4(sc*s1.x, sc*s1.y, sc*s1.z, sc*s1.w);
        op[2] = make_float4(sc*s2.x, sc*s2.y, sc*s2.z, sc*s2.w);
        op[3] = make_float4(sc*s3.x, sc*s3.y, sc*s3.z, sc*s3.w);
        out[NB * NO * 16 + idx] = sqrtf(n2 * sc * sc + EPSF);
    } else {
        float4* vp = (float4*)(v_buf + (idx << 4));
        float4 a0 = {0,0,0,0}, a1 = {0,0,0,0}, a2 = {0,0,0,0}, a3 = {0,0,0,0};
        if (mode != 0) { a0 = vp[0]; a1 = vp[1]; a2 = vp[2]; a3 = vp[3]; }
        vp[0] = make_float4(fmaf(sc,s0.x,a0.x), fmaf(sc,s0.y,a0.y), fmaf(sc,s0.z,a0.z), fmaf(sc,s0.w,a0.w));
        vp[1] = make_float4(fmaf(sc,s1.x,a1.x), fmaf(sc,s1.y,a1.y), fmaf(sc,s1.z,a1.z), fmaf(sc,s1.w,a1.w));
        vp[2] = make_float4(fmaf(sc,s2.x,a2.x), fmaf(sc,s2.y,a2.y), fmaf(sc,s2.z,a2.z), fmaf(sc,s2.w,a2.w));
        vp[3] = make_float4(fmaf(sc,s3.x,a3.x), fmaf(sc,s3.y,a3.y), fmaf(sc,s3.z,a3.z), fmaf(sc,s3.w,a3.w));
        const float4 z = {0,0,0,0};
        sp[0] = z; sp[1] = z; sp[2] = z; sp[3] = z;
    }
}

extern "C" void kernel_launch(void* const* d_in, const int* in_sizes, int n_in,
                              void* d_out, int out_size, void* d_ws, size_t ws_size,
                              hipStream_t stream) {
    const float* poses = (const float*)d_in[0];   // [B, I, 4, 4]
    // d_in[1] = input_activations — unused by the reference computation
    const float* w     = (const float*)d_in[2];   // [O, I, 4, 4]
    float* out = (float*)d_out;                   // [B,O,16] poses ++ [B,O] acts

    const size_t need = (size_t)3 * KREP * SOFF * sizeof(float);   // 3 MB
    if (ws_size >= need) {
        float* rep = (float*)d_ws;                // [3][KREP][B*O*16]
        hipMemsetAsync(rep, 0, need, stream);
        dim3 gp(NCHUNK, NBG), blk(256);
        for (int pass = 0; pass < 3; ++pass)
            caps_pass_at<<<gp, blk, 0, stream>>>(poses, w, rep, pass);
        caps_final<<<4, 256, 0, stream>>>(rep, out);
    } else {
        // proven v1-style path (tiny workspace)
        float* s_buf = (float*)d_ws;
        float* v_buf = s_buf + SOFF;
        hipMemsetAsync(s_buf, 0, SOFF * sizeof(float), stream);
        dim3 grid(FB_CHUNKS, NB), block(256);
        for (int pass = 0; pass < 3; ++pass) {
            caps_pass_fb<<<grid, block, 0, stream>>>(poses, w, v_buf, s_buf, pass);
            caps_squash_fb<<<4, 256, 0, stream>>>(s_buf, v_buf, out, pass);
        }
    }
}

// Round 8
// 205.505 us; speedup vs baseline: 4.7282x; 4.7282x over previous
//
#include <hip/hip_runtime.h>
#include <math.h>

// DenseCaps dynamic routing, MI355X. B=32, I=4096, O=32, 4x4 poses, 3 iters.
// R7 post-mortem: 4.19M global atomics serialized at TCC (345us/pass, 134MB
// WRITE) -> reverted to R5's deterministic partial-store + reduce structure.
// R8 experiment: occupancy. R5 ran 4 blocks/CU (LDS 37KB, grid 1024 = exactly
// 4/CU) at ~23us/pass vs ~6us issue floor, VALUBusy ~23%. This round halves
// the tile (I_TILE=8, LDS 18.5KB) and doubles the grid (NCHUNK=512, 2048
// blocks) with __launch_bounds__(256,6) -> 6-8 blocks/CU. Only occupancy
// changes; kernel body identical to R5.

#define NB 32
#define NI 4096
#define NO 32
#define I_TILE 8
#define NCHUNK (NI / I_TILE)        // 512
#define B_TILE 8
#define NBG (NB / B_TILE)           // 4
#define WSTR_I 578                  // LDS words per i-slab: 32*18 + 2
#define WSTR_O 18                   // padded words per o-row
#define SOFF (NB * NO * 16)         // 16384 floats per (chunk) partial slab
#define EPSF 1e-12f

__device__ __forceinline__ float4 row_mm(const float4 p, const float4 w0,
                                         const float4 w1, const float4 w2,
                                         const float4 w3) {
    float4 r;
    r.x = fmaf(p.x, w0.x, fmaf(p.y, w1.x, fmaf(p.z, w2.x, p.w * w3.x)));
    r.y = fmaf(p.x, w0.y, fmaf(p.y, w1.y, fmaf(p.z, w2.y, p.w * w3.y)));
    r.z = fmaf(p.x, w0.z, fmaf(p.y, w1.z, fmaf(p.z, w2.z, p.w * w3.z)));
    r.w = fmaf(p.x, w0.w, fmaf(p.y, w1.w, fmaf(p.z, w2.w, p.w * w3.w)));
    return r;
}

__device__ __forceinline__ float dot4(const float4 a, const float4 b) {
    return fmaf(a.x, b.x, fmaf(a.y, b.y, fmaf(a.z, b.z, a.w * b.w)));
}

__device__ __forceinline__ void fma4(float4& s, const float c, const float4 t) {
    s.x = fmaf(c, t.x, s.x);
    s.y = fmaf(c, t.y, s.y);
    s.z = fmaf(c, t.z, s.z);
    s.w = fmaf(c, t.w, s.w);
}

// x + dpp_perm(x); ctrl: 0xB1=quad_perm xor1, 0x4E=quad_perm xor2,
// 0x141=row_half_mirror (xor7), 0x140=row_mirror (xor15).
template <int CTRL>
__device__ __forceinline__ float dpp_add(float x) {
    int xi = __builtin_bit_cast(int, x);
    int yi = __builtin_amdgcn_update_dpp(0, xi, CTRL, 0xf, 0xf, false);
    return x + __builtin_bit_cast(float, yi);
}

// sum over each 32-lane half (the o-group)
__device__ __forceinline__ float sum32(float x) {
    x = dpp_add<0xB1>(x);    // xor1
    x = dpp_add<0x4E>(x);    // xor2
    x = dpp_add<0x141>(x);   // xor7 -> with above spans xor4
    x = dpp_add<0x140>(x);   // xor15 -> spans xor8 (row of 16 done)
    int t = __builtin_amdgcn_ds_swizzle(__builtin_bit_cast(int, x), 0x401F);
    return x + __builtin_bit_cast(float, t);   // xor16 within 32-lane group
}

// ---------------- pass kernel (I_TILE=8, high occupancy) ----------------
__global__ __launch_bounds__(256, 6) void caps_pass_st(
    const float* __restrict__ poses, const float* __restrict__ w,
    const float* __restrict__ v_buf, float* __restrict__ s_part,
    const int pass)
{
    __shared__ float wsm[I_TILE * WSTR_I];   // 18496 B
    const int tid    = threadIdx.x;
    const int chunk  = blockIdx.x;
    const int bgroup = blockIdx.y;
    const int ibase  = chunk * I_TILE;

    // stage w tile, fully coalesced (each o: 8 i x 64B = 512B contiguous)
    #pragma unroll
    for (int r = 0; r < 4; ++r) {
        const int idx = r * 256 + tid;     // 0..1023
        const int o_l = idx >> 5;
        const int rem = idx & 31;
        const int i_l = rem >> 2;
        const int k4  = rem & 3;
        const float4 val = *(const float4*)(
            w + (((size_t)o_l * NI + ibase + i_l) << 4) + (k4 << 2));
        float* dst = &wsm[i_l * WSTR_I + o_l * WSTR_O + (k4 << 2)];
        ((float2*)dst)[0] = make_float2(val.x, val.y);
        ((float2*)dst)[1] = make_float2(val.z, val.w);
    }

    const int o    = tid & 31;
    const int bsub = tid >> 5;
    const int b    = bgroup * B_TILE + bsub;
    const int bo   = b * NO + o;

    float4 vv0 = {0,0,0,0}, vv1 = {0,0,0,0}, vv2 = {0,0,0,0}, vv3 = {0,0,0,0};
    if (pass > 0) {
        const float4* vp = (const float4*)(v_buf + (bo << 4));
        vv0 = vp[0]; vv1 = vp[1]; vv2 = vp[2]; vv3 = vp[3];
    }

    const float*  wrow  = &wsm[o * WSTR_O];
    const float4* pbase = (const float4*)(poses + (((size_t)b * NI + ibase) << 4));

    __syncthreads();

    float4 s0 = {0,0,0,0}, s1 = {0,0,0,0}, s2 = {0,0,0,0}, s3 = {0,0,0,0};

    #pragma unroll 2
    for (int i = 0; i < I_TILE; ++i) {
        const float2* wr = (const float2*)(wrow + i * WSTR_I);
        const float2 a0 = wr[0], a1 = wr[1], a2 = wr[2], a3 = wr[3];
        const float2 a4 = wr[4], a5 = wr[5], a6 = wr[6], a7 = wr[7];
        const float4 w0 = make_float4(a0.x, a0.y, a1.x, a1.y);
        const float4 w1 = make_float4(a2.x, a2.y, a3.x, a3.y);
        const float4 w2 = make_float4(a4.x, a4.y, a5.x, a5.y);
        const float4 w3 = make_float4(a6.x, a6.y, a7.x, a7.y);
        const float4 p0 = pbase[(i << 2) + 0];
        const float4 p1 = pbase[(i << 2) + 1];
        const float4 p2 = pbase[(i << 2) + 2];
        const float4 p3 = pbase[(i << 2) + 3];

        const float4 t0 = row_mm(p0, w0, w1, w2, w3);
        const float4 t1 = row_mm(p1, w0, w1, w2, w3);
        const float4 t2 = row_mm(p2, w0, w1, w2, w3);
        const float4 t3 = row_mm(p3, w0, w1, w2, w3);

        float cc;
        if (pass == 0) {
            cc = 1.0f / 32.0f;
        } else {
            // softmax over o without max-shift: |d| bounded (~<4), exp safe.
            const float d = dot4(t0,vv0) + dot4(t1,vv1)
                          + dot4(t2,vv2) + dot4(t3,vv3);
            const float e  = __expf(d);
            const float es = sum32(e);
            cc = __fdividef(e, es);
        }
        fma4(s0, cc, t0); fma4(s1, cc, t1);
        fma4(s2, cc, t2); fma4(s3, cc, t3);
    }

    // deterministic partial store: [chunk][bo][16], fully coalesced
    float4* sp = (float4*)(s_part + ((size_t)chunk * (NB * NO) + bo) * 16);
    sp[0] = s0; sp[1] = s1; sp[2] = s2; sp[3] = s3;
}

// ---------------- reduce + squash kernel ----------------
// grid 256 x 256 thr. Block handles 64 elements (= 4 (b,o) pairs x 16 k),
// each a 512-chunk sum. thread = (c4 = tid>>6, e = tid&63).
__global__ __launch_bounds__(256) void caps_reduce(
    const float* __restrict__ s_part, float* __restrict__ v_buf,
    float* __restrict__ out, const int pass)
{
    const int e  = threadIdx.x & 63;
    const int c4 = threadIdx.x >> 6;
    const int eg = blockIdx.x * 64 + e;   // global element: bo*16 + k

    float acc = 0.0f;
    #pragma unroll 8
    for (int j = 0; j < NCHUNK / 4; ++j) {
        const int c = c4 * (NCHUNK / 4) + j;
        acc += s_part[(size_t)c * SOFF + eg];
    }
    __shared__ float red[4][64];
    red[c4][e] = acc;
    __syncthreads();

    if (threadIdx.x < 64) {
        const float a = red[0][e] + red[1][e] + red[2][e] + red[3][e];
        float x = a * a;
        #pragma unroll
        for (int msk = 8; msk >= 1; msk >>= 1)
            x += __shfl_xor(x, msk, 16);
        const float n2 = x;
        const float n  = sqrtf(n2 + EPSF);
        const float sc = (n2 / (1.0f + n2)) / n;
        if (pass < 2) {
            const float vold = (pass == 0) ? 0.0f : v_buf[eg];
            v_buf[eg] = fmaf(sc, a, vold);
        } else {
            out[eg] = sc * a;
            if ((e & 15) == 0)
                out[NB * NO * 16 + (eg >> 4)] = sqrtf(n2 * sc * sc + EPSF);
        }
    }
}

// ---------------- fallback: proven v1-style kernels (tiny ws) -------------
#define FB_CHUNKS 32
#define FB_IPB (NI / FB_CHUNKS)

__global__ __launch_bounds__(256) void caps_pass_fb(
    const float* __restrict__ poses, const float* __restrict__ w,
    const float* __restrict__ v_buf, float* __restrict__ s_buf, const int mode)
{
    const int tid   = threadIdx.x;
    const int b     = blockIdx.y;
    const int chunk = blockIdx.x;
    const int o     = tid & 31;
    const int g     = tid >> 5;

    float4 v0 = {0,0,0,0}, v1 = {0,0,0,0}, v2 = {0,0,0,0}, v3 = {0,0,0,0};
    if (mode != 0) {
        const float4* vp = (const float4*)(v_buf + (((b * NO) + o) << 4));
        v0 = vp[0]; v1 = vp[1]; v2 = vp[2]; v3 = vp[3];
    }
    float4 s0 = {0,0,0,0}, s1 = {0,0,0,0}, s2 = {0,0,0,0}, s3 = {0,0,0,0};
    const int ibase = chunk * FB_IPB + g;
    #pragma unroll 4
    for (int it = 0; it < FB_IPB / 8; ++it) {
        const int i = ibase + (it << 3);
        const float4* ppf = (const float4*)(poses + ((((size_t)b * NI) + i) << 4));
        const float4 p0 = ppf[0], p1 = ppf[1], p2 = ppf[2], p3 = ppf[3];
        const float4* wpf = (const float4*)(w + ((((size_t)o * NI) + i) << 4));
        const float4 w0 = wpf[0], w1 = wpf[1], w2 = wpf[2], w3 = wpf[3];
        const float4 t0 = row_mm(p0, w0, w1, w2, w3);
        const float4 t1 = row_mm(p1, w0, w1, w2, w3);
        const float4 t2 = row_mm(p2, w0, w1, w2, w3);
        const float4 t3 = row_mm(p3, w0, w1, w2, w3);
        float cc;
        if (mode == 0) {
            cc = 1.0f / 32.0f;
        } else {
            float d = dot4(t0,v0) + dot4(t1,v1) + dot4(t2,v2) + dot4(t3,v3);
            const float e  = __expf(d);
            const float es = sum32(e);
            cc = __fdividef(e, es);
        }
        fma4(s0, cc, t0); fma4(s1, cc, t1);
        fma4(s2, cc, t2); fma4(s3, cc, t3);
    }
    __shared__ float red[8][32][16];
    float4* rp = (float4*)&red[g][o][0];
    rp[0] = s0; rp[1] = s1; rp[2] = s2; rp[3] = s3;
    __syncthreads();
    for (int idx = tid; idx < NO * 16; idx += 256) {
        const int oo = idx >> 4;
        const int k  = idx & 15;
        float acc = red[0][oo][k];
        #pragma unroll
        for (int gg = 1; gg < 8; ++gg) acc += red[gg][oo][k];
        atomicAdd(&s_buf[(((b * NO) + oo) << 4) + k], acc);
    }
}

__global__ __launch_bounds__(256) void caps_squash_fb(
    float* __restrict__ s_buf, float* __restrict__ v_buf,
    float* __restrict__ out, const int mode)
{
    const int idx = blockIdx.x * 256 + threadIdx.x;
    if (idx >= NB * NO) return;
    float4* sp = (float4*)(s_buf + (idx << 4));
    const float4 s0 = sp[0], s1 = sp[1], s2 = sp[2], s3 = sp[3];
    const float n2 = dot4(s0,s0) + dot4(s1,s1) + dot4(s2,s2) + dot4(s3,s3);
    const float n  = sqrtf(n2 + EPSF);
    const float sc = (n2 / (1.0f + n2)) / n;
    if (mode == 2) {
        float4* op = (float4*)(out + (idx << 4));
        op[0] = make_float4(sc*s0.x, sc*s0.y, sc*s0.z, sc*s0.w);
        op[1] = make_float4(sc*s1.x, sc*s1.y, sc*s1.z, sc*s1.w);
        op[2] = make_float4(sc*s2.x, sc*s2.y, sc*s2.z, sc*s2.w);
        op[3] = make_float4(sc*s3.x, sc*s3.y, sc*s3.z, sc*s3.w);
        out[NB * NO * 16 + idx] = sqrtf(n2 * sc * sc + EPSF);
    } else {
        float4* vp = (float4*)(v_buf + (idx << 4));
        float4 a0 = {0,0,0,0}, a1 = {0,0,0,0}, a2 = {0,0,0,0}, a3 = {0,0,0,0};
        if (mode != 0) { a0 = vp[0]; a1 = vp[1]; a2 = vp[2]; a3 = vp[3]; }
        vp[0] = make_float4(fmaf(sc,s0.x,a0.x), fmaf(sc,s0.y,a0.y), fmaf(sc,s0.z,a0.z), fmaf(sc,s0.w,a0.w));
        vp[1] = make_float4(fmaf(sc,s1.x,a1.x), fmaf(sc,s1.y,a1.y), fmaf(sc,s1.z,a1.z), fmaf(sc,s1.w,a1.w));
        vp[2] = make_float4(fmaf(sc,s2.x,a2.x), fmaf(sc,s2.y,a2.y), fmaf(sc,s2.z,a2.z), fmaf(sc,s2.w,a2.w));
        vp[3] = make_float4(fmaf(sc,s3.x,a3.x), fmaf(sc,s3.y,a3.y), fmaf(sc,s3.z,a3.z), fmaf(sc,s3.w,a3.w));
        const float4 z = {0,0,0,0};
        sp[0] = z; sp[1] = z; sp[2] = z; sp[3] = z;
    }
}

extern "C" void kernel_launch(void* const* d_in, const int* in_sizes, int n_in,
                              void* d_out, int out_size, void* d_ws, size_t ws_size,
                              hipStream_t stream) {
    const float* poses = (const float*)d_in[0];   // [B, I, 4, 4]
    // d_in[1] = input_activations — unused by the reference computation
    const float* w     = (const float*)d_in[2];   // [O, I, 4, 4]
    float* out = (float*)d_out;                   // [B,O,16] poses ++ [B,O] acts

    const size_t need = ((size_t)NCHUNK * SOFF + SOFF) * sizeof(float);  // ~33.7 MB
    if (ws_size >= need) {
        float* s_part = (float*)d_ws;             // [NCHUNK][B*O][16]
        float* v_buf  = s_part + (size_t)NCHUNK * SOFF;
        dim3 gp(NCHUNK, NBG), blk(256), gr(256);
        for (int pass = 0; pass < 3; ++pass) {
            caps_pass_st<<<gp, blk, 0, stream>>>(poses, w, v_buf, s_part, pass);
            caps_reduce<<<gr, blk, 0, stream>>>(s_part, v_buf, out, pass);
        }
    } else {
        // proven v1-style path (tiny workspace)
        float* s_buf = (float*)d_ws;
        float* v_buf = s_buf + SOFF;
        hipMemsetAsync(s_buf, 0, SOFF * sizeof(float), stream);
        dim3 grid(FB_CHUNKS, NB), block(256);
        for (int pass = 0; pass < 3; ++pass) {
            caps_pass_fb<<<grid, block, 0, stream>>>(poses, w, v_buf, s_buf, pass);
            caps_squash_fb<<<4, 256, 0, stream>>>(s_buf, v_buf, out, pass);
        }
    }
}

// Round 10
// 130.453 us; speedup vs baseline: 7.4485x; 1.5753x over previous
//
#include <hip/hip_runtime.h>
#include <math.h>

// DenseCaps dynamic routing, MI355X. B=32, I=4096, O=32, 4x4 poses, 3 iters.
// R8 post-mortem: occupancy theory falsified (2x occupancy -> 2x time). The
// invariant across R1/R5/R8: ~60 cyc per wave-VMEM-instruction per CU -> the
// in-loop global poses loads (64 serial VMEM/wave) are the bound. This round:
// ZERO global loads in the inner loop. Both w and poses staged to LDS as f16
// pairs (R6 proved f16 votes, absmax 3.9e-3 << 1.8e-2): per-thread VMEM
// 77 -> 15, all batched at block start. LDS 24.6 KB -> 4 blocks/CU. Softmax
// xor16 via v_permlane16_swap (VALU pipe, guarded) instead of ds_swizzle.
// Deterministic partial stores + reduce kernel (R5 structure, NCHUNK=256).
// (R9 fix: cvt_pkrtz returns __fp16x2 -> bit_cast to v2h.)

#define NB 32
#define NI 4096
#define NO 32
#define I_TILE 16
#define NCHUNK (NI / I_TILE)        // 256
#define B_TILE 8
#define NBG (NB / B_TILE)           // 4
#define SOFF (NB * NO * 16)         // 16384 floats per (chunk) partial slab
#define EPSF 1e-12f

#define W_OSTR 10                   // words per o-row: 8 data + 2 pad
#define W_ISTR (32 * W_OSTR)        // 320 words per i-slab
#define W_WORDS (I_TILE * W_ISTR)   // 5120 words = 20 KB
#define P_WORDS (B_TILE * I_TILE * 8) // 1024 words = 4 KB

typedef _Float16 v2h __attribute__((ext_vector_type(2)));

#if __has_builtin(__builtin_amdgcn_fdot2)
__device__ __forceinline__ float fdot2(v2h a, v2h b, float c) {
    return __builtin_amdgcn_fdot2(a, b, c, false);
}
#else
__device__ __forceinline__ float fdot2(v2h a, v2h b, float c) {
    return fmaf((float)a.x, (float)b.x, fmaf((float)a.y, (float)b.y, c));
}
#endif

#if __has_builtin(__builtin_amdgcn_cvt_pkrtz)
__device__ __forceinline__ v2h pk2h(float a, float b) {
    return __builtin_bit_cast(v2h, __builtin_amdgcn_cvt_pkrtz(a, b));
}
#else
__device__ __forceinline__ v2h pk2h(float a, float b) {
    v2h r; r.x = (_Float16)a; r.y = (_Float16)b; return r;
}
#endif

__device__ __forceinline__ v2h bch(unsigned u) {
    return __builtin_bit_cast(v2h, u);
}

__device__ __forceinline__ float dot4(const float4 a, const float4 b) {
    return fmaf(a.x, b.x, fmaf(a.y, b.y, fmaf(a.z, b.z, a.w * b.w)));
}

__device__ __forceinline__ void fma4(float4& s, const float c, const float4 t) {
    s.x = fmaf(c, t.x, s.x);
    s.y = fmaf(c, t.y, s.y);
    s.z = fmaf(c, t.z, s.z);
    s.w = fmaf(c, t.w, s.w);
}

// x + dpp_perm(x); ctrl: 0xB1=quad_perm xor1, 0x4E=quad_perm xor2,
// 0x141=row_half_mirror (xor7), 0x140=row_mirror (xor15).
template <int CTRL>
__device__ __forceinline__ float dpp_add(float x) {
    int xi = __builtin_bit_cast(int, x);
    int yi = __builtin_amdgcn_update_dpp(0, xi, CTRL, 0xf, 0xf, false);
    return x + __builtin_bit_cast(float, yi);
}

// sum over each 32-lane half (the o-group)
__device__ __forceinline__ float sum32(float x) {
    x = dpp_add<0xB1>(x);    // xor1
    x = dpp_add<0x4E>(x);    // xor2
    x = dpp_add<0x141>(x);   // xor7 (8-group done)
    x = dpp_add<0x140>(x);   // xor15 (16-row done)
#if __has_builtin(__builtin_amdgcn_permlane16_swap)
    typedef unsigned uv2 __attribute__((ext_vector_type(2)));
    const unsigned xi = __builtin_bit_cast(unsigned, x);
    uv2 r = __builtin_amdgcn_permlane16_swap(xi, xi, false, false);
    return __builtin_bit_cast(float, r.x) + __builtin_bit_cast(float, r.y);
#else
    int t = __builtin_amdgcn_ds_swizzle(__builtin_bit_cast(int, x), 0x401F);
    return x + __builtin_bit_cast(float, t);   // xor16 within 32-lane group
#endif
}

// ---------------- pass kernel (all-LDS f16 inner loop) ----------------
// wsm word layout per (i,o): [m*4+z] = pair (W[2m][z], W[2m+1][z]).
// psm word layout per (b,i): [x*2+h] = pair (P[x][2h], P[x][2h+1]).
__global__ __launch_bounds__(256, 4) void caps_pass_h(
    const float* __restrict__ poses, const float* __restrict__ w,
    const float* __restrict__ v_buf, float* __restrict__ s_part,
    const int pass)
{
    __shared__ unsigned wsw[W_WORDS];   // 20480 B
    __shared__ unsigned psw[P_WORDS];   //  4096 B
    const int tid    = threadIdx.x;
    const int chunk  = blockIdx.x;
    const int bgroup = blockIdx.y;
    const int ibase  = chunk * I_TILE;

    // ---- stage w: f32 -> f16 pairs, coalesced (each 32-half: 1KB run) ----
    #pragma unroll
    for (int r = 0; r < 4; ++r) {
        const int idx = r * 256 + tid;       // 0..1023 -> (o, i, m)
        const int o_l = idx >> 5;
        const int l   = idx & 31;
        const int i_l = l >> 1;
        const int m   = l & 1;
        const float* g = w + (((size_t)o_l * NI + ibase + i_l) << 4) + (m << 3);
        const float4 A = *(const float4*)g;        // row y=2m
        const float4 B = *(const float4*)(g + 4);  // row y=2m+1
        const v2h c0 = pk2h(A.x, B.x), c1 = pk2h(A.y, B.y);
        const v2h c2 = pk2h(A.z, B.z), c3 = pk2h(A.w, B.w);
        const int base = i_l * W_ISTR + o_l * W_OSTR + (m << 2);  // even
        *(uint2*)&wsw[base]     = make_uint2(__builtin_bit_cast(unsigned, c0),
                                             __builtin_bit_cast(unsigned, c1));
        *(uint2*)&wsw[base + 2] = make_uint2(__builtin_bit_cast(unsigned, c2),
                                             __builtin_bit_cast(unsigned, c3));
    }
    // ---- stage poses: f32 -> f16 pairs, coalesced (1KB run per b) ----
    #pragma unroll
    for (int r = 0; r < 2; ++r) {
        const int idx = r * 256 + tid;       // 0..511 -> (b, i, x)
        const int b_l = idx >> 6;
        const int l   = idx & 63;
        const int i_l = l >> 2;
        const int x   = l & 3;
        const float4 row = *(const float4*)(
            poses + (((size_t)(bgroup * B_TILE + b_l) * NI + ibase + i_l) << 4)
                  + (x << 2));
        const v2h c0 = pk2h(row.x, row.y), c1 = pk2h(row.z, row.w);
        *(uint2*)&psw[((b_l * I_TILE + i_l) << 3) + (x << 1)] =
            make_uint2(__builtin_bit_cast(unsigned, c0),
                       __builtin_bit_cast(unsigned, c1));
    }

    const int o    = tid & 31;
    const int bsub = tid >> 5;
    const int b    = bgroup * B_TILE + bsub;
    const int bo   = b * NO + o;

    float4 vv0 = {0,0,0,0}, vv1 = {0,0,0,0}, vv2 = {0,0,0,0}, vv3 = {0,0,0,0};
    if (pass > 0) {
        const float4* vp = (const float4*)(v_buf + (bo << 4));
        vv0 = vp[0]; vv1 = vp[1]; vv2 = vp[2]; vv3 = vp[3];
    }

    const unsigned* wrow = &wsw[o * W_OSTR];
    const unsigned* prow = &psw[(bsub * I_TILE) << 3];

    __syncthreads();

    float4 s0 = {0,0,0,0}, s1 = {0,0,0,0}, s2 = {0,0,0,0}, s3 = {0,0,0,0};

    #pragma unroll 2
    for (int i = 0; i < I_TILE; ++i) {
        // w: 4x ds_read_b64, 10-word stride -> <=2-way (free)
        const uint2 wa = *(const uint2*)&wrow[i * W_ISTR + 0];
        const uint2 wb = *(const uint2*)&wrow[i * W_ISTR + 2];
        const uint2 wc = *(const uint2*)&wrow[i * W_ISTR + 4];
        const uint2 wd = *(const uint2*)&wrow[i * W_ISTR + 6];
        // poses: 2x ds_read_b128, broadcast (conflict-free)
        const uint4 pa = *(const uint4*)&prow[(i << 3) + 0];
        const uint4 pb = *(const uint4*)&prow[(i << 3) + 4];

        const v2h p00 = bch(pa.x), p01 = bch(pa.y);   // x0: y01, y23
        const v2h p10 = bch(pa.z), p11 = bch(pa.w);   // x1
        const v2h p20 = bch(pb.x), p21 = bch(pb.y);   // x2
        const v2h p30 = bch(pb.z), p31 = bch(pb.w);   // x3
        const v2h w00 = bch(wa.x), w01 = bch(wa.y);   // m0: z0, z1
        const v2h w02 = bch(wb.x), w03 = bch(wb.y);   // m0: z2, z3
        const v2h w10 = bch(wc.x), w11 = bch(wc.y);   // m1: z0, z1
        const v2h w12 = bch(wd.x), w13 = bch(wd.y);   // m1: z2, z3

        float4 t0, t1, t2, t3;   // votes[x][z] = sum_y P[x][y] W[y][z]
        t0.x = fdot2(p00, w00, fdot2(p01, w10, 0.0f));
        t0.y = fdot2(p00, w01, fdot2(p01, w11, 0.0f));
        t0.z = fdot2(p00, w02, fdot2(p01, w12, 0.0f));
        t0.w = fdot2(p00, w03, fdot2(p01, w13, 0.0f));
        t1.x = fdot2(p10, w00, fdot2(p11, w10, 0.0f));
        t1.y = fdot2(p10, w01, fdot2(p11, w11, 0.0f));
        t1.z = fdot2(p10, w02, fdot2(p11, w12, 0.0f));
        t1.w = fdot2(p10, w03, fdot2(p11, w13, 0.0f));
        t2.x = fdot2(p20, w00, fdot2(p21, w10, 0.0f));
        t2.y = fdot2(p20, w01, fdot2(p21, w11, 0.0f));
        t2.z = fdot2(p20, w02, fdot2(p21, w12, 0.0f));
        t2.w = fdot2(p20, w03, fdot2(p21, w13, 0.0f));
        t3.x = fdot2(p30, w00, fdot2(p31, w10, 0.0f));
        t3.y = fdot2(p30, w01, fdot2(p31, w11, 0.0f));
        t3.z = fdot2(p30, w02, fdot2(p31, w12, 0.0f));
        t3.w = fdot2(p30, w03, fdot2(p31, w13, 0.0f));

        float cc;
        if (pass == 0) {
            cc = 1.0f / 32.0f;
        } else {
            // softmax over o without max-shift: |d| bounded (~<4), exp safe.
            const float d = dot4(t0,vv0) + dot4(t1,vv1)
                          + dot4(t2,vv2) + dot4(t3,vv3);
            const float e  = __expf(d);
            const float es = sum32(e);
            cc = __fdividef(e, es);
        }
        fma4(s0, cc, t0); fma4(s1, cc, t1);
        fma4(s2, cc, t2); fma4(s3, cc, t3);
    }

    // deterministic partial store: [chunk][bo][16], fully coalesced
    float4* sp = (float4*)(s_part + ((size_t)chunk * (NB * NO) + bo) * 16);
    sp[0] = s0; sp[1] = s1; sp[2] = s2; sp[3] = s3;
}

// ---------------- reduce + squash kernel ----------------
// grid 256 x 256 thr. Block handles 64 elements (= 4 (b,o) pairs x 16 k),
// each a 256-chunk sum. thread = (c4 = tid>>6, e = tid&63).
__global__ __launch_bounds__(256) void caps_reduce(
    const float* __restrict__ s_part, float* __restrict__ v_buf,
    float* __restrict__ out, const int pass)
{
    const int e  = threadIdx.x & 63;
    const int c4 = threadIdx.x >> 6;
    const int eg = blockIdx.x * 64 + e;   // global element: bo*16 + k

    float acc = 0.0f;
    #pragma unroll 8
    for (int j = 0; j < NCHUNK / 4; ++j) {
        const int c = c4 * (NCHUNK / 4) + j;
        acc += s_part[(size_t)c * SOFF + eg];
    }
    __shared__ float red[4][64];
    red[c4][e] = acc;
    __syncthreads();

    if (threadIdx.x < 64) {
        const float a = red[0][e] + red[1][e] + red[2][e] + red[3][e];
        float x = a * a;
        #pragma unroll
        for (int msk = 8; msk >= 1; msk >>= 1)
            x += __shfl_xor(x, msk, 16);
        const float n2 = x;
        const float n  = sqrtf(n2 + EPSF);
        const float sc = (n2 / (1.0f + n2)) / n;
        if (pass < 2) {
            const float vold = (pass == 0) ? 0.0f : v_buf[eg];
            v_buf[eg] = fmaf(sc, a, vold);
        } else {
            out[eg] = sc * a;
            if ((e & 15) == 0)
                out[NB * NO * 16 + (eg >> 4)] = sqrtf(n2 * sc * sc + EPSF);
        }
    }
}

// ---------------- fallback: proven v1-style kernels (tiny ws) -------------
#define FB_CHUNKS 32
#define FB_IPB (NI / FB_CHUNKS)

__device__ __forceinline__ float4 row_mm(const float4 p, const float4 w0,
                                         const float4 w1, const float4 w2,
                                         const float4 w3) {
    float4 r;
    r.x = fmaf(p.x, w0.x, fmaf(p.y, w1.x, fmaf(p.z, w2.x, p.w * w3.x)));
    r.y = fmaf(p.x, w0.y, fmaf(p.y, w1.y, fmaf(p.z, w2.y, p.w * w3.y)));
    r.z = fmaf(p.x, w0.z, fmaf(p.y, w1.z, fmaf(p.z, w2.z, p.w * w3.z)));
    r.w = fmaf(p.x, w0.w, fmaf(p.y, w1.w, fmaf(p.z, w2.w, p.w * w3.w)));
    return r;
}

__global__ __launch_bounds__(256) void caps_pass_fb(
    const float* __restrict__ poses, const float* __restrict__ w,
    const float* __restrict__ v_buf, float* __restrict__ s_buf, const int mode)
{
    const int tid   = threadIdx.x;
    const int b     = blockIdx.y;
    const int chunk = blockIdx.x;
    const int o     = tid & 31;
    const int g     = tid >> 5;

    float4 v0 = {0,0,0,0}, v1 = {0,0,0,0}, v2 = {0,0,0,0}, v3 = {0,0,0,0};
    if (mode != 0) {
        const float4* vp = (const float4*)(v_buf + (((b * NO) + o) << 4));
        v0 = vp[0]; v1 = vp[1]; v2 = vp[2]; v3 = vp[3];
    }
    float4 s0 = {0,0,0,0}, s1 = {0,0,0,0}, s2 = {0,0,0,0}, s3 = {0,0,0,0};
    const int ibase = chunk * FB_IPB + g;
    #pragma unroll 4
    for (int it = 0; it < FB_IPB / 8; ++it) {
        const int i = ibase + (it << 3);
        const float4* ppf = (const float4*)(poses + ((((size_t)b * NI) + i) << 4));
        const float4 p0 = ppf[0], p1 = ppf[1], p2 = ppf[2], p3 = ppf[3];
        const float4* wpf = (const float4*)(w + ((((size_t)o * NI) + i) << 4));
        const float4 w0 = wpf[0], w1 = wpf[1], w2 = wpf[2], w3 = wpf[3];
        const float4 t0 = row_mm(p0, w0, w1, w2, w3);
        const float4 t1 = row_mm(p1, w0, w1, w2, w3);
        const float4 t2 = row_mm(p2, w0, w1, w2, w3);
        const float4 t3 = row_mm(p3, w0, w1, w2, w3);
        float cc;
        if (mode == 0) {
            cc = 1.0f / 32.0f;
        } else {
            float d = dot4(t0,v0) + dot4(t1,v1) + dot4(t2,v2) + dot4(t3,v3);
            const float e  = __expf(d);
            const float es = sum32(e);
            cc = __fdividef(e, es);
        }
        fma4(s0, cc, t0); fma4(s1, cc, t1);
        fma4(s2, cc, t2); fma4(s3, cc, t3);
    }
    __shared__ float red[8][32][16];
    float4* rp = (float4*)&red[g][o][0];
    rp[0] = s0; rp[1] = s1; rp[2] = s2; rp[3] = s3;
    __syncthreads();
    for (int idx = tid; idx < NO * 16; idx += 256) {
        const int oo = idx >> 4;
        const int k  = idx & 15;
        float acc = red[0][oo][k];
        #pragma unroll
        for (int gg = 1; gg < 8; ++gg) acc += red[gg][oo][k];
        atomicAdd(&s_buf[(((b * NO) + oo) << 4) + k], acc);
    }
}

__global__ __launch_bounds__(256) void caps_squash_fb(
    float* __restrict__ s_buf, float* __restrict__ v_buf,
    float* __restrict__ out, const int mode)
{
    const int idx = blockIdx.x * 256 + threadIdx.x;
    if (idx >= NB * NO) return;
    float4* sp = (float4*)(s_buf + (idx << 4));
    const float4 s0 = sp[0], s1 = sp[1], s2 = sp[2], s3 = sp[3];
    const float n2 = dot4(s0,s0) + dot4(s1,s1) + dot4(s2,s2) + dot4(s3,s3);
    const float n  = sqrtf(n2 + EPSF);
    const float sc = (n2 / (1.0f + n2)) / n;
    if (mode == 2) {
        float4* op = (float4*)(out + (idx << 4));
        op[0] = make_float4(sc*s0.x, sc*s0.y, sc*s0.z, sc*s0.w);
        op[1] = make_float4(sc*s1.x, sc*s1.y, sc*s1.z, sc*s1.w);
        op[2] = make_float4(sc*s2.x, sc*s2.y, sc*s2.z, sc*s2.w);
        op[3] = make_float4(sc*s3.x, sc*s3.y, sc*s3.z, sc*s3.w);
        out[NB * NO * 16 + idx] = sqrtf(n2 * sc * sc + EPSF);
    } else {
        float4* vp = (float4*)(v_buf + (idx << 4));
        float4 a0 = {0,0,0,0}, a1 = {0,0,0,0}, a2 = {0,0,0,0}, a3 = {0,0,0,0};
        if (mode != 0) { a0 = vp[0]; a1 = vp[1]; a2 = vp[2]; a3 = vp[3]; }
        vp[0] = make_float4(fmaf(sc,s0.x,a0.x), fmaf(sc,s0.y,a0.y), fmaf(sc,s0.z,a0.z), fmaf(sc,s0.w,a0.w));
        vp[1] = make_float4(fmaf(sc,s1.x,a1.x), fmaf(sc,s1.y,a1.y), fmaf(sc,s1.z,a1.z), fmaf(sc,s1.w,a1.w));
        vp[2] = make_float4(fmaf(sc,s2.x,a2.x), fmaf(sc,s2.y,a2.y), fmaf(sc,s2.z,a2.z), fmaf(sc,s2.w,a2.w));
        vp[3] = make_float4(fmaf(sc,s3.x,a3.x), fmaf(sc,s3.y,a3.y), fmaf(sc,s3.z,a3.z), fmaf(sc,s3.w,a3.w));
        const float4 z = {0,0,0,0};
        sp[0] = z; sp[1] = z; sp[2] = z; sp[3] = z;
    }
}

extern "C" void kernel_launch(void* const* d_in, const int* in_sizes, int n_in,
                              void* d_out, int out_size, void* d_ws, size_t ws_size,
                              hipStream_t stream) {
    const float* poses = (const float*)d_in[0];   // [B, I, 4, 4]
    // d_in[1] = input_activations — unused by the reference computation
    const float* w     = (const float*)d_in[2];   // [O, I, 4, 4]
    float* out = (float*)d_out;                   // [B,O,16] poses ++ [B,O] acts

    const size_t need = ((size_t)NCHUNK * SOFF + SOFF) * sizeof(float);  // ~16.9 MB
    if (ws_size >= need) {
        float* s_part = (float*)d_ws;             // [NCHUNK][B*O][16]
        float* v_buf  = s_part + (size_t)NCHUNK * SOFF;
        dim3 gp(NCHUNK, NBG), blk(256), gr(256);
        for (int pass = 0; pass < 3; ++pass) {
            caps_pass_h<<<gp, blk, 0, stream>>>(poses, w, v_buf, s_part, pass);
            caps_reduce<<<gr, blk, 0, stream>>>(s_part, v_buf, out, pass);
        }
    } else {
        // proven v1-style path (tiny workspace)
        float* s_buf = (float*)d_ws;
        float* v_buf = s_buf + SOFF;
        (void)hipMemsetAsync(s_buf, 0, SOFF * sizeof(float), stream);
        dim3 grid(FB_CHUNKS, NB), block(256);
        for (int pass = 0; pass < 3; ++pass) {
            caps_pass_fb<<<grid, block, 0, stream>>>(poses, w, v_buf, s_buf, pass);
            caps_squash_fb<<<4, 256, 0, stream>>>(s_buf, v_buf, out, pass);
        }
    }
}